// Round 1
// baseline (739.203 us; speedup 1.0000x reference)
//
#include <hip/hip_runtime.h>
#include <hip/hip_bf16.h>

typedef unsigned short u16;
typedef __attribute__((ext_vector_type(8))) short bf16x8;
typedef __attribute__((ext_vector_type(4))) float f32x4;

#define B_   32
#define L_   2048
#define H_   1024
#define E_   512
#define KCAT 2560   // 2H + E
#define NR   2048   // 2H

// Persistent device scratch (avoids d_ws sizing concerns; every buffer is
// fully rewritten each call, so re-poisoning of d_ws is irrelevant).
__device__ __align__(256) u16   g_WencT[H_*H_];      // bf16, [n][k] (transposed W_enc)
__device__ __align__(256) float g_gdec[B_*H_];       // h@W_dec + b_dec + b_enc
__device__ __align__(256) float g_scores[B_*L_];     // pre-softmax scores
__device__ __align__(256) float g_cat[B_*KCAT];      // [c_t, h, x]
__device__ __align__(256) float g_pct[32][B_*H_];    // c_t partials (per l-chunk)
__device__ __align__(256) float g_part[40][B_*NR];   // r_t partials (per k-chunk)

__device__ __forceinline__ u16 f2b(float f) {        // fp32 -> bf16 RNE
  unsigned x = __float_as_uint(f);
  return (u16)((x + 0x7fffu + ((x >> 16) & 1u)) >> 16);
}

__device__ __forceinline__ void gll16(const void* g, void* l) {
  __builtin_amdgcn_global_load_lds(
      (const __attribute__((address_space(1))) void*)g,
      (__attribute__((address_space(3))) void*)l, 16, 0, 0);
}

__device__ __forceinline__ float tanh_fast(float x) {
  float e = __expf(2.0f * x);
  return 1.0f - 2.0f / (e + 1.0f);   // no overflow: e=inf -> 1, e=0 -> -1
}

// ---------------------------------------------------------------- W_enc^T bf16
__global__ __launch_bounds__(256) void k_transpose(const float* __restrict__ W) {
  __shared__ float t[64 * 65];                 // +1 pad: conflict-free
  const int n0 = blockIdx.x * 64, k0 = blockIdx.y * 64;
  const int c = threadIdx.x & 63, q = threadIdx.x >> 6;
  #pragma unroll
  for (int rr = 0; rr < 16; rr++) {
    int r = rr * 4 + q;
    t[c * 65 + r] = W[(size_t)(k0 + r) * H_ + n0 + c];   // coalesced along n
  }
  __syncthreads();
  #pragma unroll
  for (int nn = 0; nn < 16; nn++) {
    int nl = nn * 4 + q;
    g_WencT[(size_t)(n0 + nl) * H_ + k0 + c] = f2b(t[nl * 65 + c]); // coalesced along k
  }
}

// ------------------------------------------------------------------ init pass
__global__ __launch_bounds__(256) void k_init(const float* __restrict__ h,
                                              const float* __restrict__ x,
                                              const float* __restrict__ b_enc,
                                              const float* __restrict__ b_dec,
                                              const float* __restrict__ b_v) {
  int id = blockIdx.x * 256 + threadIdx.x;     // 704*256 = 180224 exact
  if (id < 32768) { g_gdec[id] = b_dec[id & 1023] + b_enc[id & 1023]; return; }
  id -= 32768;
  if (id < 65536) { g_scores[id] = b_v[0]; return; }
  id -= 65536;
  { // cat: [c_t(0..1023) | h(1024..2047) | x(2048..2559)]
    int b = id / KCAT, c = id - b * KCAT;
    float v = 0.0f;
    if (c >= 1024 && c < 2048) v = h[b * H_ + (c - 1024)];
    else if (c >= 2048)        v = x[b * E_ + (c - 2048)];
    g_cat[id] = v;
  }
}

// --------------------------------------------------- gamma_dec += h @ W_dec
__global__ __launch_bounds__(256) void k_gdec(const float* __restrict__ h,
                                              const float* __restrict__ Wd) {
  const int b = blockIdx.y;
  const int hc = blockIdx.x & 3, kc = blockIdx.x >> 2;
  const int col = hc * 256 + threadIdx.x;
  const float* hb = h + b * H_ + kc * 256;
  const float* wp = Wd + (size_t)(kc * 256) * H_ + col;
  float acc = 0.0f;
  #pragma unroll 4
  for (int k = 0; k < 256; k++) acc = fmaf(hb[k], wp[(size_t)k * H_], acc);
  atomicAdd(&g_gdec[b * H_ + col], acc);
}

// ------------- fused: gamma=ctx@W_enc (+gdec) -> tanh -> dot(W_v) -> scores
// BM=64 rows (one b), BN=1024 (full H), BK=32, 16 waves, dbuf LDS, XOR-swizzle.
__global__ __launch_bounds__(1024, 4) void k_scores(const float* __restrict__ ctx,
                                                    const float* __restrict__ Wv) {
  __shared__ u16 Ab[2][64 * 32];        // 8 KB  : ctx tile, [row][k] swizzled
  __shared__ u16 Bb[2][1024 * 32];      // 128 KB: W_enc^T tile, [col][k] swizzled
  __shared__ float ssum[64];
  const int tid = threadIdx.x;
  const int bid = blockIdx.x;
  const int b  = bid >> 5;
  const int l0 = (bid & 31) << 6;
  if (tid < 64) ssum[tid] = 0.0f;

  // A staging: 1024 threads cover 64 rows x 16 float2 (k-pairs)
  const int arow = tid >> 4, akp = tid & 15;
  const float* actx = ctx + ((size_t)(b * L_ + l0 + arow)) * H_ + akp * 2;
  const unsigned aidx = arow * 32 + ((akp * 2) ^ ((arow & 3) << 3)); // u16 units

  // B staging geometry (global_load_lds: linear LDS dest, pre-swizzled source)
  const unsigned bnl = tid >> 2, bslot = tid & 3;

  f32x4 acc[4][4];
  #pragma unroll
  for (int i = 0; i < 4; i++) {
    #pragma unroll
    for (int j = 0; j < 4; j++) acc[i][j] = (f32x4)0.0f;
  }

  const int lane = tid & 63;
  const int w    = tid >> 6;            // 0..15, owns cols [w*64, w*64+64)
  const int r16  = lane & 15;
  const int g8   = (lane >> 4) * 8;     // k-slot base (u16 units)

  auto stageB = [&](int buf, int ks) {
    const unsigned k0b = ks * 64;       // byte offset along k
    #pragma unroll
    for (int q = 0; q < 4; q++) {
      unsigned nl = q * 256 + bnl;
      unsigned ga = nl * 2048 + k0b + ((bslot ^ (nl & 3)) << 4);
      gll16((const char*)g_WencT + ga, (char*)&Bb[buf][0] + q * 16384 + tid * 16);
    }
  };

  { // prologue: stage tile 0
    float2 av = *(const float2*)actx;
    stageB(0, 0);
    *(ushort2*)&Ab[0][aidx] = make_ushort2(f2b(av.x), f2b(av.y));
  }
  __syncthreads();

  #pragma unroll 2
  for (int ks = 0; ks < 32; ks++) {
    const int cur = ks & 1;
    float2 av;
    if (ks < 31) {                       // issue-early (T14): loads before MFMA
      av = *(const float2*)(actx + (ks + 1) * 32);
      stageB(cur ^ 1, ks + 1);
    }
    bf16x8 af[4], bfv[4];
    #pragma unroll
    for (int mt = 0; mt < 4; mt++) {
      int row = mt * 16 + r16;
      af[mt] = *(const bf16x8*)&Ab[cur][row * 32 + (g8 ^ ((row & 3) << 3))];
    }
    #pragma unroll
    for (int nt = 0; nt < 4; nt++) {
      int col = w * 64 + nt * 16 + r16;
      bfv[nt] = *(const bf16x8*)&Bb[cur][col * 32 + (g8 ^ ((col & 3) << 3))];
    }
    #pragma unroll
    for (int mt = 0; mt < 4; mt++) {
      #pragma unroll
      for (int nt = 0; nt < 4; nt++)
        acc[mt][nt] = __builtin_amdgcn_mfma_f32_16x16x32_bf16(af[mt], bfv[nt],
                                                              acc[mt][nt], 0, 0, 0);
    }
    if (ks < 31) {                       // write-late: hide ctx HBM latency
      *(ushort2*)&Ab[cur ^ 1][aidx] = make_ushort2(f2b(av.x), f2b(av.y));
    }
    __syncthreads();
  }

  // epilogue: tanh(gamma + gdec) . W_v, reduce over this wave's 64 cols
  float wv[4], gd[4];
  #pragma unroll
  for (int nt = 0; nt < 4; nt++) {
    int col = w * 64 + nt * 16 + r16;
    wv[nt] = Wv[col];
    gd[nt] = g_gdec[b * H_ + col];
  }
  const int rbase = (lane >> 4) * 4;
  #pragma unroll
  for (int mt = 0; mt < 4; mt++) {
    #pragma unroll
    for (int r = 0; r < 4; r++) {
      float p = 0.0f;
      #pragma unroll
      for (int nt = 0; nt < 4; nt++)
        p += tanh_fast(acc[mt][nt][r] + gd[nt]) * wv[nt];
      p += __shfl_xor(p, 1);
      p += __shfl_xor(p, 2);
      p += __shfl_xor(p, 4);
      p += __shfl_xor(p, 8);             // sum over 16 col-lanes
      if (r16 == 0) atomicAdd(&ssum[mt * 16 + rbase + r], p);
    }
  }
  __syncthreads();
  if (tid < 64) atomicAdd(&g_scores[b * L_ + l0 + tid], ssum[tid]);
}

// ------------------------------------------------------------------- softmax
__global__ __launch_bounds__(256) void k_softmax(float* __restrict__ wout) {
  const int b = blockIdx.x, tid = threadIdx.x;
  __shared__ float red[4];
  float v[8]; float m = -1e30f;
  #pragma unroll
  for (int i = 0; i < 8; i++) {
    v[i] = g_scores[b * L_ + i * 256 + tid];
    m = fmaxf(m, v[i]);
  }
  #pragma unroll
  for (int s = 1; s < 64; s <<= 1) m = fmaxf(m, __shfl_xor(m, s));
  if ((tid & 63) == 0) red[tid >> 6] = m;
  __syncthreads();
  m = fmaxf(fmaxf(red[0], red[1]), fmaxf(red[2], red[3]));
  __syncthreads();
  float s = 0.0f;
  #pragma unroll
  for (int i = 0; i < 8; i++) { v[i] = __expf(v[i] - m); s += v[i]; }
  #pragma unroll
  for (int t = 1; t < 64; t <<= 1) s += __shfl_xor(s, t);
  if ((tid & 63) == 0) red[tid >> 6] = s;
  __syncthreads();
  const float inv = 1.0f / (red[0] + red[1] + red[2] + red[3]);
  #pragma unroll
  for (int i = 0; i < 8; i++) wout[b * L_ + i * 256 + tid] = v[i] * inv;
}

// --------------------------------------------- c_t partials: w[b,l] * ctx row
__global__ __launch_bounds__(256) void k_ct(const float* __restrict__ ctx,
                                            const float* __restrict__ wout) {
  const int lc = blockIdx.x, b = blockIdx.y, tid = threadIdx.x;
  const int l0 = lc * 64;
  __shared__ float wl[64];
  if (tid < 64) wl[tid] = wout[b * L_ + l0 + tid];
  __syncthreads();
  const float4* cp = (const float4*)(ctx + ((size_t)(b * L_ + l0)) * H_) + tid;
  float4 a = {0.f, 0.f, 0.f, 0.f};
  #pragma unroll 4
  for (int i = 0; i < 64; i++) {
    float4 vv = cp[(size_t)i * 256];
    float wv = wl[i];
    a.x = fmaf(vv.x, wv, a.x);
    a.y = fmaf(vv.y, wv, a.y);
    a.z = fmaf(vv.z, wv, a.z);
    a.w = fmaf(vv.w, wv, a.w);
  }
  *(float4*)&g_pct[lc][b * H_ + tid * 4] = a;
}

__global__ __launch_bounds__(256) void k_ctred() {
  const int id = blockIdx.x * 256 + threadIdx.x;   // b*1024 + hcol
  float s = 0.0f;
  #pragma unroll 8
  for (int lc = 0; lc < 32; lc++) s += g_pct[lc][id];
  g_cat[(id >> 10) * KCAT + (id & 1023)] = s;
}

// ------------------------------------------- r_t partials: cat @ W_r (k-split)
__global__ __launch_bounds__(256) void k_r1(const float* __restrict__ Wr) {
  const int nc = blockIdx.x, kc = blockIdx.y, tid = threadIdx.x;
  __shared__ float cl[32][64];
  #pragma unroll
  for (int i = 0; i < 8; i++) {
    int flat = i * 256 + tid;
    cl[flat >> 6][flat & 63] = g_cat[(flat >> 6) * KCAT + kc * 64 + (flat & 63)];
  }
  __syncthreads();
  float acc[32];
  #pragma unroll
  for (int b2 = 0; b2 < 32; b2++) acc[b2] = 0.0f;
  const float* wp = Wr + (size_t)(kc * 64) * NR + nc * 256 + tid;
  #pragma unroll 4
  for (int k4 = 0; k4 < 16; k4++) {
    float w0 = wp[(size_t)(k4 * 4 + 0) * NR], w1 = wp[(size_t)(k4 * 4 + 1) * NR],
          w2 = wp[(size_t)(k4 * 4 + 2) * NR], w3 = wp[(size_t)(k4 * 4 + 3) * NR];
    #pragma unroll
    for (int b2 = 0; b2 < 32; b2++) {
      const float4 c4 = *(const float4*)&cl[b2][k4 * 4];   // uniform addr: broadcast
      acc[b2] = fmaf(c4.x, w0, acc[b2]);
      acc[b2] = fmaf(c4.y, w1, acc[b2]);
      acc[b2] = fmaf(c4.z, w2, acc[b2]);
      acc[b2] = fmaf(c4.w, w3, acc[b2]);
    }
  }
  float* pp = &g_part[kc][nc * 256 + tid];
  #pragma unroll
  for (int b2 = 0; b2 < 32; b2++) pp[b2 * NR] = acc[b2];
}

// ----------------------------------------------- sum k-partials, +b_r, maxout
__global__ __launch_bounds__(256) void k_maxout(const float* __restrict__ b_r,
                                                float* __restrict__ out) {
  const int id = blockIdx.x * 256 + threadIdx.x;   // 0..32767 = b*1024 + j
  const int j = id & 1023;
  float r0 = b_r[2 * j], r1 = b_r[2 * j + 1];
  #pragma unroll 8
  for (int kc = 0; kc < 40; kc++) {
    const float2 v = *(const float2*)&g_part[kc][2 * id];  // [b][2j],[b][2j+1]
    r0 += v.x; r1 += v.y;
  }
  out[id] = fmaxf(r0, r1);
}

extern "C" void kernel_launch(void* const* d_in, const int* in_sizes, int n_in,
                              void* d_out, int out_size, void* d_ws, size_t ws_size,
                              hipStream_t stream) {
  (void)in_sizes; (void)n_in; (void)d_ws; (void)ws_size; (void)out_size;
  const float* h     = (const float*)d_in[0];
  const float* x     = (const float*)d_in[1];
  const float* ctx   = (const float*)d_in[2];
  const float* W_enc = (const float*)d_in[3];
  const float* b_enc = (const float*)d_in[4];
  const float* W_dec = (const float*)d_in[5];
  const float* b_dec = (const float*)d_in[6];
  const float* W_v   = (const float*)d_in[7];
  const float* b_v   = (const float*)d_in[8];
  const float* W_r   = (const float*)d_in[9];
  const float* b_r   = (const float*)d_in[10];
  float* out  = (float*)d_out;          // [32,1024] maxout output
  float* wout = out + 32768;            // [32,2048] attention weights

  k_transpose<<<dim3(16, 16), 256, 0, stream>>>(W_enc);
  k_init<<<704, 256, 0, stream>>>(h, x, b_enc, b_dec, b_v);
  k_gdec<<<dim3(16, 32), 256, 0, stream>>>(h, W_dec);
  k_scores<<<1024, 1024, 0, stream>>>(ctx, W_v);
  k_softmax<<<32, 256, 0, stream>>>(wout);
  k_ct<<<dim3(32, 32), 256, 0, stream>>>(ctx, wout);
  k_ctred<<<128, 256, 0, stream>>>();
  k_r1<<<dim3(8, 40), 256, 0, stream>>>(W_r);
  k_maxout<<<128, 256, 0, stream>>>(b_r, out);
}

// Round 2
// 669.319 us; speedup vs baseline: 1.1044x; 1.1044x over previous
//
#include <hip/hip_runtime.h>
#include <hip/hip_bf16.h>

typedef unsigned short u16;
typedef __attribute__((ext_vector_type(8))) short bf16x8;
typedef __attribute__((ext_vector_type(4))) float f32x4;

#define B_   32
#define L_   2048
#define H_   1024
#define E_   512
#define KCAT 2560   // 2H + E
#define NR   2048   // 2H

// Persistent device scratch (all fully rewritten every call).
__device__ __align__(256) u16   g_WencT[H_*H_];      // bf16, [n][k] (transposed W_enc)
__device__ __align__(256) u16   g_ctx16[(size_t)B_*L_*H_]; // bf16 copy of contexts
__device__ __align__(256) float g_gdec[B_*H_];       // h@W_dec + b_dec + b_enc
__device__ __align__(256) float g_scores[B_*L_];     // pre-softmax scores
__device__ __align__(256) float g_cat[B_*KCAT];      // [c_t, h, x]
__device__ __align__(256) float g_pct[32][B_*H_];    // c_t partials (per l-chunk)
__device__ __align__(256) float g_part[40][B_*NR];   // r_t partials (per k-chunk)

__device__ __forceinline__ u16 f2b(float f) {        // fp32 -> bf16 RNE
  unsigned x = __float_as_uint(f);
  return (u16)((x + 0x7fffu + ((x >> 16) & 1u)) >> 16);
}
__device__ __forceinline__ float b2f(u16 u) {
  return __uint_as_float(((unsigned)u) << 16);
}

__device__ __forceinline__ void gll16(const void* g, void* l) {
  __builtin_amdgcn_global_load_lds(
      (const __attribute__((address_space(1))) void*)g,
      (__attribute__((address_space(3))) void*)l, 16, 0, 0);
}

__device__ __forceinline__ float tanh_fast(float x) {
  float e = __expf(2.0f * x);
  return 1.0f - 2.0f / (e + 1.0f);   // e=inf -> 1, e=0 -> -1
}

// ---------------------------------------------------------------- W_enc^T bf16
__global__ __launch_bounds__(256) void k_transpose(const float* __restrict__ W) {
  __shared__ float t[64 * 65];                 // +1 pad: conflict-free
  const int n0 = blockIdx.x * 64, k0 = blockIdx.y * 64;
  const int c = threadIdx.x & 63, q = threadIdx.x >> 6;
  #pragma unroll
  for (int rr = 0; rr < 16; rr++) {
    int r = rr * 4 + q;
    t[c * 65 + r] = W[(size_t)(k0 + r) * H_ + n0 + c];   // coalesced along n
  }
  __syncthreads();
  #pragma unroll
  for (int nn = 0; nn < 16; nn++) {
    int nl = nn * 4 + q;
    g_WencT[(size_t)(n0 + nl) * H_ + k0 + c] = f2b(t[nl * 65 + c]); // coalesced along k
  }
}

// ------------------------------------------------------------- ctx -> bf16
__global__ __launch_bounds__(256) void k_cvt(const float* __restrict__ ctx) {
  const size_t gid = (size_t)blockIdx.x * 256 + threadIdx.x;  // 4096*256 = 1048576
  #pragma unroll
  for (int it = 0; it < 8; it++) {
    const size_t c = gid + (size_t)it * 1048576;             // vec8 chunk id
    const float4 a = *(const float4*)(ctx + c * 8);
    const float4 b = *(const float4*)(ctx + c * 8 + 4);
    bf16x8 o;
    o[0] = (short)f2b(a.x); o[1] = (short)f2b(a.y);
    o[2] = (short)f2b(a.z); o[3] = (short)f2b(a.w);
    o[4] = (short)f2b(b.x); o[5] = (short)f2b(b.y);
    o[6] = (short)f2b(b.z); o[7] = (short)f2b(b.w);
    *(bf16x8*)&g_ctx16[c * 8] = o;
  }
}

// ------------------------------------------------------------------ init pass
__global__ __launch_bounds__(256) void k_init(const float* __restrict__ h,
                                              const float* __restrict__ x,
                                              const float* __restrict__ b_enc,
                                              const float* __restrict__ b_dec,
                                              const float* __restrict__ b_v) {
  int id = blockIdx.x * 256 + threadIdx.x;     // 704*256 = 180224 exact
  if (id < 32768) { g_gdec[id] = b_dec[id & 1023] + b_enc[id & 1023]; return; }
  id -= 32768;
  if (id < 65536) { g_scores[id] = b_v[0]; return; }
  id -= 65536;
  { // cat: [c_t(0..1023) | h(1024..2047) | x(2048..2559)]
    int b = id / KCAT, c = id - b * KCAT;
    float v = 0.0f;
    if (c >= 1024 && c < 2048) v = h[b * H_ + (c - 1024)];
    else if (c >= 2048)        v = x[b * E_ + (c - 2048)];
    g_cat[id] = v;
  }
}

// --------------------------------------------------- gamma_dec += h @ W_dec
__global__ __launch_bounds__(256) void k_gdec(const float* __restrict__ h,
                                              const float* __restrict__ Wd) {
  const int b = blockIdx.y;
  const int hc = blockIdx.x & 3, kc = blockIdx.x >> 2;
  const int col = hc * 256 + threadIdx.x;
  const float* hb = h + b * H_ + kc * 256;
  const float* wp = Wd + (size_t)(kc * 256) * H_ + col;
  float acc = 0.0f;
  #pragma unroll 8
  for (int k = 0; k < 256; k++) acc = fmaf(hb[k], wp[(size_t)k * H_], acc);
  atomicAdd(&g_gdec[b * H_ + col], acc);
}

// ------------- fused: gamma=ctx@W_enc (+gdec) -> tanh -> dot(W_v) -> scores
// 256x256 tile, BK=64, 512 thr / 8 waves (2M x 4N), dbuf LDS, 1 barrier/K-tile.
#define BK 64
__global__ __launch_bounds__(512, 2) void k_scores(const float* __restrict__ Wv) {
  __shared__ u16 Ab[2][256 * BK];      // 32 KB per buf
  __shared__ u16 Bb[2][256 * BK];
  __shared__ float ssum[256];
  const int tid = threadIdx.x;

  // bijective XCD-chunked swizzle (nwg=1024, 1024%8==0)
  const int orig = blockIdx.x;
  const int wg = (orig & 7) * 128 + (orig >> 3);
  const int mtile = wg >> 2;               // 0..255
  const int ntile = wg & 3;                // 0..3
  const int b  = mtile >> 3;
  const int l0 = (mtile & 7) * 256;

  const char* Asrc = (const char*)(g_ctx16 + ((size_t)(b * L_ + l0)) * H_);
  const char* Bsrc = (const char*)(g_WencT + (size_t)(ntile * 256) * H_);

  // staging geometry: 2048 16B-slots per 32KB tile; thread covers 4 (q*512+tid)
  size_t soff[4];
  #pragma unroll
  for (int q = 0; q < 4; q++) {
    const int sid = q * 512 + tid;
    const int row = sid >> 3, slot = sid & 7;
    soff[q] = (size_t)row * 2048 + (size_t)((slot ^ (row & 7)) << 4);
  }

  const int lane = tid & 63, wid = tid >> 6;
  const int wm = wid >> 2, wn = wid & 3;   // wave tile: rows wm*128+, cols wn*64+
  const int r16 = lane & 15, g = lane >> 4;
  const int base_a = (wm * 128 + r16) * BK;    // u16 units
  const int base_b = (wn * 64 + r16) * BK;

  if (tid < 256) ssum[tid] = 0.0f;

  f32x4 acc[8][4];
  #pragma unroll
  for (int i = 0; i < 8; i++)
    #pragma unroll
    for (int j = 0; j < 4; j++) acc[i][j] = (f32x4)0.0f;

  auto stage = [&](int buf, int ks) {
    const size_t kb = (size_t)ks * 128;    // byte offset along K
    #pragma unroll
    for (int q = 0; q < 4; q++)
      gll16(Asrc + soff[q] + kb, (char*)&Ab[buf][0] + q * 8192 + tid * 16);
    #pragma unroll
    for (int q = 0; q < 4; q++)
      gll16(Bsrc + soff[q] + kb, (char*)&Bb[buf][0] + q * 8192 + tid * 16);
  };

  stage(0, 0);
  __syncthreads();

  for (int ks = 0; ks < 16; ks++) {
    const int cur = ks & 1;
    if (ks < 15) stage(cur ^ 1, ks + 1);   // issue-early; lands before next barrier
    #pragma unroll
    for (int kk = 0; kk < 2; kk++) {
      const int po = (((kk * 4 + g) ^ (r16 & 7)) << 3);   // physical slot, u16 units
      bf16x8 bf0 = *(const bf16x8*)&Bb[cur][base_b + 0 * 1024 + po];
      bf16x8 bf1 = *(const bf16x8*)&Bb[cur][base_b + 1 * 1024 + po];
      bf16x8 bf2 = *(const bf16x8*)&Bb[cur][base_b + 2 * 1024 + po];
      bf16x8 bf3 = *(const bf16x8*)&Bb[cur][base_b + 3 * 1024 + po];
      #pragma unroll
      for (int mt = 0; mt < 8; mt++) {
        bf16x8 am = *(const bf16x8*)&Ab[cur][base_a + mt * 1024 + po];
        acc[mt][0] = __builtin_amdgcn_mfma_f32_16x16x32_bf16(am, bf0, acc[mt][0], 0, 0, 0);
        acc[mt][1] = __builtin_amdgcn_mfma_f32_16x16x32_bf16(am, bf1, acc[mt][1], 0, 0, 0);
        acc[mt][2] = __builtin_amdgcn_mfma_f32_16x16x32_bf16(am, bf2, acc[mt][2], 0, 0, 0);
        acc[mt][3] = __builtin_amdgcn_mfma_f32_16x16x32_bf16(am, bf3, acc[mt][3], 0, 0, 0);
      }
    }
    __syncthreads();   // drains gll16 (vmcnt0) + LDS reads (lgkmcnt0), swaps bufs
  }

  // epilogue: tanh(gamma + gdec) . W_v, reduce over cols
  const int colb = ntile * 256 + wn * 64;
  float wv[4], gd[4];
  #pragma unroll
  for (int q = 0; q < 4; q++) {
    const int col = colb + q * 16 + r16;
    wv[q] = Wv[col];
    gd[q] = g_gdec[b * H_ + col];
  }
  #pragma unroll
  for (int mt = 0; mt < 8; mt++) {
    #pragma unroll
    for (int r = 0; r < 4; r++) {
      float p = 0.0f;
      #pragma unroll
      for (int q = 0; q < 4; q++)
        p += tanh_fast(acc[mt][q][r] + gd[q]) * wv[q];
      p += __shfl_xor(p, 1);
      p += __shfl_xor(p, 2);
      p += __shfl_xor(p, 4);
      p += __shfl_xor(p, 8);             // sum over 16 col-lanes
      if (r16 == 0) atomicAdd(&ssum[wm * 128 + mt * 16 + g * 4 + r], p);
    }
  }
  __syncthreads();
  if (tid < 256) atomicAdd(&g_scores[b * L_ + l0 + tid], ssum[tid]);
}

// ------------------------------------------------------------------- softmax
__global__ __launch_bounds__(256) void k_softmax(float* __restrict__ wout) {
  const int b = blockIdx.x, tid = threadIdx.x;
  __shared__ float red[4];
  float v[8]; float m = -1e30f;
  #pragma unroll
  for (int i = 0; i < 8; i++) {
    v[i] = g_scores[b * L_ + i * 256 + tid];
    m = fmaxf(m, v[i]);
  }
  #pragma unroll
  for (int s = 1; s < 64; s <<= 1) m = fmaxf(m, __shfl_xor(m, s));
  if ((tid & 63) == 0) red[tid >> 6] = m;
  __syncthreads();
  m = fmaxf(fmaxf(red[0], red[1]), fmaxf(red[2], red[3]));
  __syncthreads();
  float s = 0.0f;
  #pragma unroll
  for (int i = 0; i < 8; i++) { v[i] = __expf(v[i] - m); s += v[i]; }
  #pragma unroll
  for (int t = 1; t < 64; t <<= 1) s += __shfl_xor(s, t);
  if ((tid & 63) == 0) red[tid >> 6] = s;
  __syncthreads();
  const float inv = 1.0f / (red[0] + red[1] + red[2] + red[3]);
  #pragma unroll
  for (int i = 0; i < 8; i++) wout[b * L_ + i * 256 + tid] = v[i] * inv;
}

// --------------------------------------------- c_t partials: w[b,l] * ctx row
__global__ __launch_bounds__(256) void k_ct(const float* __restrict__ wout) {
  const int lc = blockIdx.x, b = blockIdx.y;           // 16 l-chunks of 128
  const int cg = threadIdx.x & 127, rh = threadIdx.x >> 7;
  __shared__ float wl[128];
  if (threadIdx.x < 128) wl[threadIdx.x] = wout[b * L_ + lc * 128 + threadIdx.x];
  __syncthreads();
  const u16* cp = g_ctx16 + ((size_t)(b * L_ + lc * 128 + rh * 64)) * H_ + cg * 8;
  float a[8] = {0.f, 0.f, 0.f, 0.f, 0.f, 0.f, 0.f, 0.f};
  #pragma unroll 8
  for (int i = 0; i < 64; i++) {
    const bf16x8 v = *(const bf16x8*)(cp + (size_t)i * H_);
    const float w = wl[rh * 64 + i];
    #pragma unroll
    for (int j = 0; j < 8; j++) a[j] = fmaf(b2f((u16)v[j]), w, a[j]);
  }
  #pragma unroll
  for (int j = 0; j < 8; j++)
    g_pct[lc * 2 + rh][b * H_ + cg * 8 + j] = a[j];
}

__global__ __launch_bounds__(256) void k_ctred() {
  const int id = blockIdx.x * 256 + threadIdx.x;   // b*1024 + hcol
  float s = 0.0f;
  #pragma unroll 8
  for (int lc = 0; lc < 32; lc++) s += g_pct[lc][id];
  g_cat[(id >> 10) * KCAT + (id & 1023)] = s;
}

// ------------------------------------------- r_t partials: cat @ W_r (k-split)
__global__ __launch_bounds__(256) void k_r1(const float* __restrict__ Wr) {
  const int nc = blockIdx.x, kc = blockIdx.y, tid = threadIdx.x;
  __shared__ float cl[32][64];
  #pragma unroll
  for (int i = 0; i < 8; i++) {
    int flat = i * 256 + tid;
    cl[flat >> 6][flat & 63] = g_cat[(flat >> 6) * KCAT + kc * 64 + (flat & 63)];
  }
  __syncthreads();
  float acc[32];
  #pragma unroll
  for (int b2 = 0; b2 < 32; b2++) acc[b2] = 0.0f;
  const float* wp = Wr + (size_t)(kc * 64) * NR + nc * 256 + tid;
  #pragma unroll 4
  for (int k4 = 0; k4 < 16; k4++) {
    float w0 = wp[(size_t)(k4 * 4 + 0) * NR], w1 = wp[(size_t)(k4 * 4 + 1) * NR],
          w2 = wp[(size_t)(k4 * 4 + 2) * NR], w3 = wp[(size_t)(k4 * 4 + 3) * NR];
    #pragma unroll
    for (int b2 = 0; b2 < 32; b2++) {
      const float4 c4 = *(const float4*)&cl[b2][k4 * 4];   // uniform addr: broadcast
      acc[b2] = fmaf(c4.x, w0, acc[b2]);
      acc[b2] = fmaf(c4.y, w1, acc[b2]);
      acc[b2] = fmaf(c4.z, w2, acc[b2]);
      acc[b2] = fmaf(c4.w, w3, acc[b2]);
    }
  }
  float* pp = &g_part[kc][nc * 256 + tid];
  #pragma unroll
  for (int b2 = 0; b2 < 32; b2++) pp[b2 * NR] = acc[b2];
}

// ----------------------------------------------- sum k-partials, +b_r, maxout
__global__ __launch_bounds__(256) void k_maxout(const float* __restrict__ b_r,
                                                float* __restrict__ out) {
  const int id = blockIdx.x * 256 + threadIdx.x;   // 0..32767 = b*1024 + j
  const int j = id & 1023;
  float r0 = b_r[2 * j], r1 = b_r[2 * j + 1];
  #pragma unroll 8
  for (int kc = 0; kc < 40; kc++) {
    const float2 v = *(const float2*)&g_part[kc][2 * id];  // [b][2j],[b][2j+1]
    r0 += v.x; r1 += v.y;
  }
  out[id] = fmaxf(r0, r1);
}

extern "C" void kernel_launch(void* const* d_in, const int* in_sizes, int n_in,
                              void* d_out, int out_size, void* d_ws, size_t ws_size,
                              hipStream_t stream) {
  (void)in_sizes; (void)n_in; (void)d_ws; (void)ws_size; (void)out_size;
  const float* h     = (const float*)d_in[0];
  const float* x     = (const float*)d_in[1];
  const float* ctx   = (const float*)d_in[2];
  const float* W_enc = (const float*)d_in[3];
  const float* b_enc = (const float*)d_in[4];
  const float* W_dec = (const float*)d_in[5];
  const float* b_dec = (const float*)d_in[6];
  const float* W_v   = (const float*)d_in[7];
  const float* b_v   = (const float*)d_in[8];
  const float* W_r   = (const float*)d_in[9];
  const float* b_r   = (const float*)d_in[10];
  float* out  = (float*)d_out;          // [32,1024] maxout output
  float* wout = out + 32768;            // [32,2048] attention weights

  k_transpose<<<dim3(16, 16), 256, 0, stream>>>(W_enc);
  k_cvt<<<4096, 256, 0, stream>>>(ctx);
  k_init<<<704, 256, 0, stream>>>(h, x, b_enc, b_dec, b_v);
  k_gdec<<<dim3(16, 32), 256, 0, stream>>>(h, W_dec);
  k_scores<<<1024, 512, 0, stream>>>(W_v);
  k_softmax<<<32, 256, 0, stream>>>(wout);
  k_ct<<<dim3(16, 32), 256, 0, stream>>>(wout);
  k_ctred<<<128, 256, 0, stream>>>();
  k_r1<<<dim3(8, 40), 256, 0, stream>>>(W_r);
  k_maxout<<<128, 256, 0, stream>>>(b_r, out);
}

// Round 3
// 657.774 us; speedup vs baseline: 1.1238x; 1.0176x over previous
//
#include <hip/hip_runtime.h>
#include <hip/hip_bf16.h>

typedef unsigned short u16;
typedef __attribute__((ext_vector_type(8))) short bf16x8;
typedef __attribute__((ext_vector_type(4))) float f32x4;

#define B_   32
#define L_   2048
#define H_   1024
#define E_   512
#define KCAT 2560   // 2H + E
#define NR   2048   // 2H

// Persistent device scratch (all fully rewritten every call).
__device__ __align__(256) u16   g_WencT[H_*H_];      // bf16, [n][k] (transposed W_enc)
__device__ __align__(256) u16   g_ctx16[(size_t)B_*L_*H_]; // bf16 copy of contexts
__device__ __align__(256) float g_gdec[B_*H_];       // h@W_dec + b_dec + b_enc
__device__ __align__(256) float g_scores[B_*L_];     // pre-softmax scores
__device__ __align__(256) float g_cat[B_*KCAT];      // [c_t, h, x]
__device__ __align__(256) float g_pct[32][B_*H_];    // c_t partials (per l-chunk)
__device__ __align__(256) float g_part[40][B_*NR];   // r_t partials (per k-chunk)

__device__ __forceinline__ u16 f2b(float f) {        // fp32 -> bf16 RNE
  unsigned x = __float_as_uint(f);
  return (u16)((x + 0x7fffu + ((x >> 16) & 1u)) >> 16);
}
__device__ __forceinline__ float b2f(u16 u) {
  return __uint_as_float(((unsigned)u) << 16);
}

__device__ __forceinline__ void gll16(const void* g, void* l) {
  __builtin_amdgcn_global_load_lds(
      (const __attribute__((address_space(1))) void*)g,
      (__attribute__((address_space(3))) void*)l, 16, 0, 0);
}

__device__ __forceinline__ float tanh_fast(float x) {
  float e = __expf(2.0f * x);
  return 1.0f - 2.0f / (e + 1.0f);   // e=inf -> 1, e=0 -> -1
}

// ---------------------------------------------------------------- W_enc^T bf16
__global__ __launch_bounds__(256) void k_transpose(const float* __restrict__ W) {
  __shared__ float t[64 * 65];                 // +1 pad: conflict-free
  const int n0 = blockIdx.x * 64, k0 = blockIdx.y * 64;
  const int c = threadIdx.x & 63, q = threadIdx.x >> 6;
  #pragma unroll
  for (int rr = 0; rr < 16; rr++) {
    int r = rr * 4 + q;
    t[c * 65 + r] = W[(size_t)(k0 + r) * H_ + n0 + c];   // coalesced along n
  }
  __syncthreads();
  #pragma unroll
  for (int nn = 0; nn < 16; nn++) {
    int nl = nn * 4 + q;
    g_WencT[(size_t)(n0 + nl) * H_ + k0 + c] = f2b(t[nl * 65 + c]); // coalesced along k
  }
}

// ------------------------------------------------------------- ctx -> bf16
__global__ __launch_bounds__(256) void k_cvt(const float* __restrict__ ctx) {
  const size_t gid = (size_t)blockIdx.x * 256 + threadIdx.x;  // 4096*256 = 1048576
  #pragma unroll
  for (int it = 0; it < 8; it++) {
    const size_t c = gid + (size_t)it * 1048576;             // vec8 chunk id
    const float4 a = *(const float4*)(ctx + c * 8);
    const float4 b = *(const float4*)(ctx + c * 8 + 4);
    bf16x8 o;
    o[0] = (short)f2b(a.x); o[1] = (short)f2b(a.y);
    o[2] = (short)f2b(a.z); o[3] = (short)f2b(a.w);
    o[4] = (short)f2b(b.x); o[5] = (short)f2b(b.y);
    o[6] = (short)f2b(b.z); o[7] = (short)f2b(b.w);
    *(bf16x8*)&g_ctx16[c * 8] = o;
  }
}

// ------------------------------------------------------------------ init pass
__global__ __launch_bounds__(256) void k_init(const float* __restrict__ h,
                                              const float* __restrict__ x,
                                              const float* __restrict__ b_enc,
                                              const float* __restrict__ b_dec,
                                              const float* __restrict__ b_v) {
  int id = blockIdx.x * 256 + threadIdx.x;     // 704*256 = 180224 exact
  if (id < 32768) { g_gdec[id] = b_dec[id & 1023] + b_enc[id & 1023]; return; }
  id -= 32768;
  if (id < 65536) { g_scores[id] = b_v[0]; return; }
  id -= 65536;
  { // cat: [c_t(0..1023) | h(1024..2047) | x(2048..2559)]
    int b = id / KCAT, c = id - b * KCAT;
    float v = 0.0f;
    if (c >= 1024 && c < 2048) v = h[b * H_ + (c - 1024)];
    else if (c >= 2048)        v = x[b * E_ + (c - 2048)];
    g_cat[id] = v;
  }
}

// --------------------------------------------------- gamma_dec += h @ W_dec
__global__ __launch_bounds__(256) void k_gdec(const float* __restrict__ h,
                                              const float* __restrict__ Wd) {
  const int b = blockIdx.y;
  const int hc = blockIdx.x & 3, kc = blockIdx.x >> 2;
  const int col = hc * 256 + threadIdx.x;
  const float* hb = h + b * H_ + kc * 256;
  const float* wp = Wd + (size_t)(kc * 256) * H_ + col;
  float acc = 0.0f;
  #pragma unroll 8
  for (int k = 0; k < 256; k++) acc = fmaf(hb[k], wp[(size_t)k * H_], acc);
  atomicAdd(&g_gdec[b * H_ + col], acc);
}

// ------------- fused: gamma=ctx@W_enc (+gdec) -> tanh -> dot(W_v) -> scores
// 256x256 tile, BK=64, 512 thr / 8 waves (2M x 4N).
// Counted-vmcnt 2-phase pipeline (T3+T4): per phase {issue 4 gll16 ->
// s_waitcnt vmcnt(8) -> s_barrier -> 12 ds_read_b128 -> setprio MFMA x32}.
// Each wait clears stages issued TWO phases earlier (~600+cy flight).
// LDS layout per operand: [buf][kkhalf][256 rows][4 slots of 16B], slot
// XOR-swizzled with row&3 on BOTH source addr and read addr (rule 21).
#define BK 64
__global__ __launch_bounds__(512, 2) void k_scores(const float* __restrict__ Wv) {
  __shared__ u16 Ab[2][2][256 * 32];   // 16 KB per half-buf
  __shared__ u16 Bb[2][2][256 * 32];
  __shared__ float ssum[256];
  const int tid = threadIdx.x;

  // bijective XCD-chunked swizzle (nwg=1024, 1024%8==0)
  const int orig = blockIdx.x;
  const int wg = (orig & 7) * 128 + (orig >> 3);
  const int mtile = wg >> 2;               // 0..255
  const int ntile = wg & 3;                // 0..3
  const int b  = mtile >> 3;
  const int l0 = (mtile & 7) * 256;

  const char* Asrc = (const char*)(g_ctx16 + ((size_t)(b * L_ + l0)) * H_);
  const char* Bsrc = (const char*)(g_WencT + (size_t)(ntile * 256) * H_);

  // staging: per K-half, 1024 16B-slots; thread covers sid = tid, tid+512.
  // sid -> row = sid>>2, pslot = sid&3; source logical slot = pslot^(row&3)
  size_t soff[2];
  #pragma unroll
  for (int q = 0; q < 2; q++) {
    const int sid = q * 512 + tid;
    const int row = sid >> 2, ps = sid & 3;
    soff[q] = (size_t)row * 2048 + (size_t)((ps ^ (row & 3)) << 4);
  }

  const int lane = tid & 63, wid = tid >> 6;
  const int wm = wid >> 2, wn = wid & 3;   // wave tile: rows wm*128+, cols wn*64+
  const int r16 = lane & 15, g = lane >> 4;
  const int swz = ((g ^ (r16 & 3)) << 3);          // u16 units, constant per lane
  const int aoff = (wm * 128 + r16) * 32 + swz;    // + mt*512
  const int boff = (wn * 64 + r16) * 32 + swz;     // + nt*512

  if (tid < 256) ssum[tid] = 0.0f;

  f32x4 acc[8][4];
  #pragma unroll
  for (int i = 0; i < 8; i++)
    #pragma unroll
    for (int j = 0; j < 4; j++) acc[i][j] = (f32x4)0.0f;

  // stage one K-half of one tile: 4 gll16 per thread (A x2, B x2)
  auto stage = [&](int buf, int half, int ks) {
    const size_t kb = (size_t)ks * 128 + (size_t)half * 64;
    #pragma unroll
    for (int q = 0; q < 2; q++) {
      gll16(Asrc + soff[q] + kb, (char*)&Ab[buf][half][0] + q * 8192 + tid * 16);
      gll16(Bsrc + soff[q] + kb, (char*)&Bb[buf][half][0] + q * 8192 + tid * 16);
    }
  };

  stage(0, 0, 0);            // prologue: tile 0 both halves
  stage(0, 1, 0);

  #pragma unroll 2
  for (int p = 0; p < 32; p++) {
    const int t = p >> 1, kk = p & 1;
    const int cur = t & 1;
    // issue-early: stage (t+1, kk); tail wraps to tile 0 (dead buffer, harmless)
    stage(cur ^ 1, kk, (t + 1) & 15);
    asm volatile("s_waitcnt vmcnt(8)" ::: "memory");  // clears phase p-2 stages
    __builtin_amdgcn_s_barrier();                     // cross-wave visibility

    const u16* Ah = &Ab[cur][kk][0];
    const u16* Bh = &Bb[cur][kk][0];
    bf16x8 bfv[4], af[8];
    #pragma unroll
    for (int nt = 0; nt < 4; nt++) bfv[nt] = *(const bf16x8*)&Bh[boff + nt * 512];
    #pragma unroll
    for (int mt = 0; mt < 8; mt++) af[mt] = *(const bf16x8*)&Ah[aoff + mt * 512];

    __builtin_amdgcn_s_setprio(1);
    #pragma unroll
    for (int mt = 0; mt < 8; mt++) {
      acc[mt][0] = __builtin_amdgcn_mfma_f32_16x16x32_bf16(af[mt], bfv[0], acc[mt][0], 0, 0, 0);
      acc[mt][1] = __builtin_amdgcn_mfma_f32_16x16x32_bf16(af[mt], bfv[1], acc[mt][1], 0, 0, 0);
      acc[mt][2] = __builtin_amdgcn_mfma_f32_16x16x32_bf16(af[mt], bfv[2], acc[mt][2], 0, 0, 0);
      acc[mt][3] = __builtin_amdgcn_mfma_f32_16x16x32_bf16(af[mt], bfv[3], acc[mt][3], 0, 0, 0);
    }
    __builtin_amdgcn_s_setprio(0);
  }

  // epilogue: tanh(gamma + gdec) . W_v, reduce over cols
  const int colb = ntile * 256 + wn * 64;
  float wv[4], gd[4];
  #pragma unroll
  for (int q = 0; q < 4; q++) {
    const int col = colb + q * 16 + r16;
    wv[q] = Wv[col];
    gd[q] = g_gdec[b * H_ + col];
  }
  #pragma unroll
  for (int mt = 0; mt < 8; mt++) {
    #pragma unroll
    for (int r = 0; r < 4; r++) {
      float p = 0.0f;
      #pragma unroll
      for (int q = 0; q < 4; q++)
        p += tanh_fast(acc[mt][q][r] + gd[q]) * wv[q];
      p += __shfl_xor(p, 1);
      p += __shfl_xor(p, 2);
      p += __shfl_xor(p, 4);
      p += __shfl_xor(p, 8);             // sum over 16 col-lanes
      if (r16 == 0) atomicAdd(&ssum[wm * 128 + mt * 16 + g * 4 + r], p);
    }
  }
  __syncthreads();   // full drain once (also drains tail junk stages) - fine
  if (tid < 256) atomicAdd(&g_scores[b * L_ + l0 + tid], ssum[tid]);
}

// ------------------------------------------------------------------- softmax
__global__ __launch_bounds__(256) void k_softmax(float* __restrict__ wout) {
  const int b = blockIdx.x, tid = threadIdx.x;
  __shared__ float red[4];
  float v[8]; float m = -1e30f;
  #pragma unroll
  for (int i = 0; i < 8; i++) {
    v[i] = g_scores[b * L_ + i * 256 + tid];
    m = fmaxf(m, v[i]);
  }
  #pragma unroll
  for (int s = 1; s < 64; s <<= 1) m = fmaxf(m, __shfl_xor(m, s));
  if ((tid & 63) == 0) red[tid >> 6] = m;
  __syncthreads();
  m = fmaxf(fmaxf(red[0], red[1]), fmaxf(red[2], red[3]));
  __syncthreads();
  float s = 0.0f;
  #pragma unroll
  for (int i = 0; i < 8; i++) { v[i] = __expf(v[i] - m); s += v[i]; }
  #pragma unroll
  for (int t = 1; t < 64; t <<= 1) s += __shfl_xor(s, t);
  if ((tid & 63) == 0) red[tid >> 6] = s;
  __syncthreads();
  const float inv = 1.0f / (red[0] + red[1] + red[2] + red[3]);
  #pragma unroll
  for (int i = 0; i < 8; i++) wout[b * L_ + i * 256 + tid] = v[i] * inv;
}

// --------------------------------------------- c_t partials: w[b,l] * ctx row
__global__ __launch_bounds__(256) void k_ct(const float* __restrict__ wout) {
  const int lc = blockIdx.x, b = blockIdx.y;           // 16 l-chunks of 128
  const int cg = threadIdx.x & 127, rh = threadIdx.x >> 7;
  __shared__ float wl[128];
  if (threadIdx.x < 128) wl[threadIdx.x] = wout[b * L_ + lc * 128 + threadIdx.x];
  __syncthreads();
  const u16* cp = g_ctx16 + ((size_t)(b * L_ + lc * 128 + rh * 64)) * H_ + cg * 8;
  float a[8] = {0.f, 0.f, 0.f, 0.f, 0.f, 0.f, 0.f, 0.f};
  #pragma unroll 8
  for (int i = 0; i < 64; i++) {
    const bf16x8 v = *(const bf16x8*)(cp + (size_t)i * H_);
    const float w = wl[rh * 64 + i];
    #pragma unroll
    for (int j = 0; j < 8; j++) a[j] = fmaf(b2f((u16)v[j]), w, a[j]);
  }
  #pragma unroll
  for (int j = 0; j < 8; j++)
    g_pct[lc * 2 + rh][b * H_ + cg * 8 + j] = a[j];
}

__global__ __launch_bounds__(256) void k_ctred() {
  const int id = blockIdx.x * 256 + threadIdx.x;   // b*1024 + hcol
  float s = 0.0f;
  #pragma unroll 8
  for (int lc = 0; lc < 32; lc++) s += g_pct[lc][id];
  g_cat[(id >> 10) * KCAT + (id & 1023)] = s;
}

// ------------------------------------------- r_t partials: cat @ W_r (k-split)
__global__ __launch_bounds__(256) void k_r1(const float* __restrict__ Wr) {
  const int nc = blockIdx.x, kc = blockIdx.y, tid = threadIdx.x;
  __shared__ float cl[32][64];
  #pragma unroll
  for (int i = 0; i < 8; i++) {
    int flat = i * 256 + tid;
    cl[flat >> 6][flat & 63] = g_cat[(flat >> 6) * KCAT + kc * 64 + (flat & 63)];
  }
  __syncthreads();
  float acc[32];
  #pragma unroll
  for (int b2 = 0; b2 < 32; b2++) acc[b2] = 0.0f;
  const float* wp = Wr + (size_t)(kc * 64) * NR + nc * 256 + tid;
  #pragma unroll 4
  for (int k4 = 0; k4 < 16; k4++) {
    float w0 = wp[(size_t)(k4 * 4 + 0) * NR], w1 = wp[(size_t)(k4 * 4 + 1) * NR],
          w2 = wp[(size_t)(k4 * 4 + 2) * NR], w3 = wp[(size_t)(k4 * 4 + 3) * NR];
    #pragma unroll
    for (int b2 = 0; b2 < 32; b2++) {
      const float4 c4 = *(const float4*)&cl[b2][k4 * 4];   // uniform addr: broadcast
      acc[b2] = fmaf(c4.x, w0, acc[b2]);
      acc[b2] = fmaf(c4.y, w1, acc[b2]);
      acc[b2] = fmaf(c4.z, w2, acc[b2]);
      acc[b2] = fmaf(c4.w, w3, acc[b2]);
    }
  }
  float* pp = &g_part[kc][nc * 256 + tid];
  #pragma unroll
  for (int b2 = 0; b2 < 32; b2++) pp[b2 * NR] = acc[b2];
}

// ----------------------------------------------- sum k-partials, +b_r, maxout
__global__ __launch_bounds__(256) void k_maxout(const float* __restrict__ b_r,
                                                float* __restrict__ out) {
  const int id = blockIdx.x * 256 + threadIdx.x;   // 0..32767 = b*1024 + j
  const int j = id & 1023;
  float r0 = b_r[2 * j], r1 = b_r[2 * j + 1];
  #pragma unroll 8
  for (int kc = 0; kc < 40; kc++) {
    const float2 v = *(const float2*)&g_part[kc][2 * id];  // [b][2j],[b][2j+1]
    r0 += v.x; r1 += v.y;
  }
  out[id] = fmaxf(r0, r1);
}

extern "C" void kernel_launch(void* const* d_in, const int* in_sizes, int n_in,
                              void* d_out, int out_size, void* d_ws, size_t ws_size,
                              hipStream_t stream) {
  (void)in_sizes; (void)n_in; (void)d_ws; (void)ws_size; (void)out_size;
  const float* h     = (const float*)d_in[0];
  const float* x     = (const float*)d_in[1];
  const float* ctx   = (const float*)d_in[2];
  const float* W_enc = (const float*)d_in[3];
  const float* b_enc = (const float*)d_in[4];
  const float* W_dec = (const float*)d_in[5];
  const float* b_dec = (const float*)d_in[6];
  const float* W_v   = (const float*)d_in[7];
  const float* b_v   = (const float*)d_in[8];
  const float* W_r   = (const float*)d_in[9];
  const float* b_r   = (const float*)d_in[10];
  float* out  = (float*)d_out;          // [32,1024] maxout output
  float* wout = out + 32768;            // [32,2048] attention weights

  k_transpose<<<dim3(16, 16), 256, 0, stream>>>(W_enc);
  k_cvt<<<4096, 256, 0, stream>>>(ctx);
  k_init<<<704, 256, 0, stream>>>(h, x, b_enc, b_dec, b_v);
  k_gdec<<<dim3(16, 32), 256, 0, stream>>>(h, W_dec);
  k_scores<<<1024, 512, 0, stream>>>(W_v);
  k_softmax<<<32, 256, 0, stream>>>(wout);
  k_ct<<<dim3(16, 32), 256, 0, stream>>>(wout);
  k_ctred<<<128, 256, 0, stream>>>();
  k_r1<<<dim3(8, 40), 256, 0, stream>>>(W_r);
  k_maxout<<<128, 256, 0, stream>>>(b_r, out);
}